// Round 4
// baseline (1408.525 us; speedup 1.0000x reference)
//
#include <hip/hip_runtime.h>

typedef unsigned short u16;

__device__ __forceinline__ float b2f(unsigned int ubits) {
  union { unsigned int i; float f; } cv; cv.i = ubits << 16; return cv.f;
}
__device__ __forceinline__ u16 f2b(float f) {
  unsigned int u = __builtin_bit_cast(unsigned int, f);
  u += 0x7fffu + ((u >> 16) & 1u);   // RNE
  return (u16)(u >> 16);
}
__device__ __forceinline__ float lrelu(float v) { return v > 0.f ? v : 0.2f * v; }
// read float from buffer whose dtype is decided at runtime (bf16 vs f32)
__device__ __forceinline__ float rdf(bool isbf, const void* p, int idx) {
  return isbf ? b2f((unsigned int)((const u16*)p)[idx]) : ((const float*)p)[idx];
}

// ---------------- dtype detection: 1 = bf16, 0 = f32 ----------------
__global__ void detect_kernel(const u16* __restrict__ probe, int* __restrict__ flag) {
  if (threadIdx.x == 0 && blockIdx.x == 0) {
    int cnt = 0;
    for (int i = 0; i < 256; i++) {
      unsigned int u = probe[i];
      unsigned int e = (u >> 7) & 0xFFu;
      if ((u & 0x7fffu) == 0 || (e >= 60 && e <= 191)) cnt++;
    }
    *flag = (cnt >= 240) ? 1 : 0;
  }
}

// ---------------- CSR build ----------------
__global__ __launch_bounds__(256) void hist_kernel(const int* __restrict__ dst, int E,
                                                   int* __restrict__ deg) {
  int i = blockIdx.x * 256 + threadIdx.x;
  if (i < E) atomicAdd(deg + dst[i], 1);
}

__global__ __launch_bounds__(1024) void scan_kernel(const int* __restrict__ deg,
                                                    int* __restrict__ rowptr,
                                                    int* __restrict__ cursor, int n) {
  __shared__ int wsum[16];
  __shared__ int carry_s;
  int tid = threadIdx.x, lane = tid & 63, wid = tid >> 6;
  if (tid == 0) carry_s = 0;
  __syncthreads();
  for (int base = 0; base < n; base += 4096) {
    int i0 = base + tid * 4;
    int v0 = 0, v1 = 0, v2 = 0, v3 = 0;
    if (i0 + 3 < n) {
      int4 t4 = *(const int4*)(deg + i0);
      v0 = t4.x; v1 = t4.y; v2 = t4.z; v3 = t4.w;
    } else {
      if (i0 < n) v0 = deg[i0];
      if (i0 + 1 < n) v1 = deg[i0 + 1];
      if (i0 + 2 < n) v2 = deg[i0 + 2];
      if (i0 + 3 < n) v3 = deg[i0 + 3];
    }
    int local = v0 + v1 + v2 + v3;
    int incl = local;
#pragma unroll
    for (int off = 1; off < 64; off <<= 1) {
      int t = __shfl_up(incl, off, 64);
      if (lane >= off) incl += t;
    }
    if (lane == 63) wsum[wid] = incl;
    __syncthreads();
    int woff = 0;
    for (int w = 0; w < wid; w++) woff += wsum[w];
    int run = carry_s + woff + incl - local;
    if (i0 < n)     { rowptr[i0] = run;     cursor[i0] = run; }     run += v0;
    if (i0 + 1 < n) { rowptr[i0 + 1] = run; cursor[i0 + 1] = run; } run += v1;
    if (i0 + 2 < n) { rowptr[i0 + 2] = run; cursor[i0 + 2] = run; } run += v2;
    if (i0 + 3 < n) { rowptr[i0 + 3] = run; cursor[i0 + 3] = run; }
    __syncthreads();
    if (tid == 1023) carry_s = carry_s + woff + incl;
    __syncthreads();
  }
  if (tid == 0) rowptr[n] = carry_s;
}

__global__ __launch_bounds__(256) void fill_kernel(const int* __restrict__ src,
                                                   const int* __restrict__ dst, int E,
                                                   int* __restrict__ cursor,
                                                   int* __restrict__ colarr) {
  int i = blockIdx.x * 256 + threadIdx.x;
  if (i < E) {
    int p = atomicAdd(cursor + dst[i], 1);
    colarr[p] = src[i];
  }
}

// ---------------- simple VALU GEMM: one block per row ----------------
// C[i, colofs:colofs+ncols] = A[i,:] @ W   (W in original [K][ncols] layout, native dtype)
// OUT_F32: store float32, else store bf16(u16).
template <bool RAW_A, bool HAS_ME, bool HAS_EPI, bool OUT_F32>
__global__ __launch_bounds__(128) void simple_gemm(
    const void* __restrict__ Av, int lda,
    const void* __restrict__ me,
    const void* __restrict__ Wv,
    int K, void* __restrict__ C, int ldc, int colofs, int ncols,
    const void* __restrict__ bias, const int* __restrict__ flagp) {
  __shared__ float row[256];
  bool isbf = (*flagp != 0);
  int i = blockIdx.x;
  int tid = threadIdx.x;
  for (int k = tid; k < K; k += 128) {
    float v;
    if (RAW_A) {
      if (isbf) {
        unsigned int raw = ((const u16*)Av)[(long)i * lda + k];
        if (HAS_ME && (raw & 0x7fffu) == 0) raw = ((const u16*)me)[k];
        v = b2f(raw);
      } else {
        unsigned int raw = ((const unsigned int*)Av)[(long)i * lda + k];
        if (HAS_ME && (raw & 0x7fffffffu) == 0) {
          v = ((const float*)me)[k];
        } else {
          v = __builtin_bit_cast(float, raw);
        }
      }
    } else {
      v = b2f((unsigned int)((const u16*)Av)[(long)i * lda + k]);
    }
    row[k] = v;
  }
  __syncthreads();
  if (tid < ncols) {
    float acc = 0.f;
    for (int k = 0; k < K; k++) acc += row[k] * rdf(isbf, Wv, k * ncols + tid);
    if (HAS_EPI) {
      acc += rdf(isbf, bias, tid);
      acc = lrelu(acc);
    }
    if (OUT_F32) {
      ((float*)C)[(long)i * ldc + colofs + tid] = acc;
    } else {
      ((u16*)C)[(long)i * ldc + colofs + tid] = f2b(acc);
    }
  }
}

// ---------------- aggregation + GIN epilogue (one wave per node, 256 feats = [e|c], bf16 in/out) ----------------
__global__ __launch_bounds__(256) void agg_kernel(
    const u16* __restrict__ t, const int* __restrict__ rowptr, const int* __restrict__ colarr,
    const void* __restrict__ epsE, const void* __restrict__ epsC,
    const void* __restrict__ bE, const void* __restrict__ bC,
    u16* __restrict__ u, int N, const int* __restrict__ flagp) {
  int node = blockIdx.x * 4 + (threadIdx.x >> 6);
  if (node >= N) return;
  bool isbf = (*flagp != 0);
  int lane = threadIdx.x & 63;
  int f0 = lane << 2;  // 4 features per lane
  const u16* tb = t + f0;
  float a0 = 0.f, a1 = 0.f, a2 = 0.f, a3 = 0.f;
  int e = rowptr[node], e1 = rowptr[node + 1];
  for (; e + 4 <= e1; e += 4) {
    int c0 = colarr[e], c1 = colarr[e + 1], c2 = colarr[e + 2], c3 = colarr[e + 3];
    uint2 p0 = *(const uint2*)(tb + ((long)c0 << 8));
    uint2 p1 = *(const uint2*)(tb + ((long)c1 << 8));
    uint2 p2 = *(const uint2*)(tb + ((long)c2 << 8));
    uint2 p3 = *(const uint2*)(tb + ((long)c3 << 8));
    a0 += b2f(p0.x & 0xffffu); a1 += b2f(p0.x >> 16); a2 += b2f(p0.y & 0xffffu); a3 += b2f(p0.y >> 16);
    a0 += b2f(p1.x & 0xffffu); a1 += b2f(p1.x >> 16); a2 += b2f(p1.y & 0xffffu); a3 += b2f(p1.y >> 16);
    a0 += b2f(p2.x & 0xffffu); a1 += b2f(p2.x >> 16); a2 += b2f(p2.y & 0xffffu); a3 += b2f(p2.y >> 16);
    a0 += b2f(p3.x & 0xffffu); a1 += b2f(p3.x >> 16); a2 += b2f(p3.y & 0xffffu); a3 += b2f(p3.y >> 16);
  }
  for (; e < e1; e++) {
    int c = colarr[e];
    uint2 p = *(const uint2*)(tb + ((long)c << 8));
    a0 += b2f(p.x & 0xffffu); a1 += b2f(p.x >> 16); a2 += b2f(p.y & 0xffffu); a3 += b2f(p.y >> 16);
  }
  // self term: (1+eps)*t_i + self-loop t_i = (2+eps)*t_i
  uint2 ps = *(const uint2*)(tb + ((long)node << 8));
  bool isE = (lane < 32);
  float eps2 = 2.0f + rdf(isbf, isE ? epsE : epsC, 0);
  const void* bp = isE ? bE : bC;
  int bi = isE ? f0 : (f0 - 128);
  float bb0 = rdf(isbf, bp, bi);
  float bb1 = rdf(isbf, bp, bi + 1);
  float bb2 = rdf(isbf, bp, bi + 2);
  float bb3 = rdf(isbf, bp, bi + 3);
  a0 = lrelu(a0 + eps2 * b2f(ps.x & 0xffffu) + bb0);
  a1 = lrelu(a1 + eps2 * b2f(ps.x >> 16)     + bb1);
  a2 = lrelu(a2 + eps2 * b2f(ps.y & 0xffffu) + bb2);
  a3 = lrelu(a3 + eps2 * b2f(ps.y >> 16)     + bb3);
  unsigned int lo = ((unsigned int)f2b(a1) << 16) | f2b(a0);
  unsigned int hi = ((unsigned int)f2b(a3) << 16) | f2b(a2);
  *(uint2*)(u + ((long)node << 8) + f0) = make_uint2(lo, hi);
}

// ---------------- central-node MLP (f32 in, f32 out) ----------------
__global__ __launch_bounds__(128) void mlp_kernel(
    const float* __restrict__ outbuf, const int* __restrict__ central,
    const void* __restrict__ Wp1, const void* __restrict__ bp1,
    const void* __restrict__ Wp2, const void* __restrict__ bp2,
    float* __restrict__ logits, const int* __restrict__ flagp) {
  __shared__ float h1[128];
  __shared__ float o[8];
  bool isbf = (*flagp != 0);
  int b = blockIdx.x, tid = threadIdx.x;
  int node = central[b];
  if (tid < 8) o[tid] = outbuf[node * 8 + tid];
  __syncthreads();
  float s = rdf(isbf, bp1, tid);
#pragma unroll
  for (int k = 0; k < 8; k++) s += o[k] * rdf(isbf, Wp1, k * 128 + tid);
  h1[tid] = fmaxf(s, 0.f);
  __syncthreads();
  if (tid < 8) {
    float s2 = rdf(isbf, bp2, tid);
    for (int k = 0; k < 128; k++) s2 += h1[k] * rdf(isbf, Wp2, k * 8 + tid);
    logits[b * 8 + tid] = s2;
  }
}

extern "C" void kernel_launch(void* const* d_in, const int* in_sizes, int n_in,
                              void* d_out, int out_size, void* d_ws, size_t ws_size,
                              hipStream_t stream) {
  const void* x    = d_in[0];
  const void* c    = d_in[1];
  const int* eidx  = (const int*)d_in[2];
  const int* cidx  = (const int*)d_in[3];
  const void* me_x = d_in[4];
  const void* me_c = d_in[5];
  const void* W1e  = d_in[6];
  const void* b1e  = d_in[7];
  const void* e1e  = d_in[8];
  const void* W2e  = d_in[9];
  const void* b2e  = d_in[10];
  const void* e2e  = d_in[11];
  const void* W1c  = d_in[12];
  const void* b1c  = d_in[13];
  const void* e1c  = d_in[14];
  const void* W2c  = d_in[15];
  const void* b2c  = d_in[16];
  const void* e2c  = d_in[17];
  const void* Wm   = d_in[18];
  const void* bm   = d_in[19];
  const void* Wp1  = d_in[20];
  const void* bp1  = d_in[21];
  const void* Wp2  = d_in[22];
  const void* bp2  = d_in[23];

  const int N = in_sizes[0] / 256;   // 50000
  const int E = in_sizes[2] / 2;     // 800000
  const int Cn = in_sizes[3];        // 512
  const int* src = eidx;
  const int* dst = eidx + E;

  char* ws = (char*)d_ws;
  int* deg    = (int*)(ws + 0);          // 200000 B
  int* rowptr = (int*)(ws + 200192);     // 200004 B
  int* cursor = (int*)(ws + 400384);     // 200000 B
  int* colarr = (int*)(ws + 600576);     // 3200000 B
  u16* tbuf   = (u16*)(ws + 3800576);    // 25600000 B  [N,256] bf16
  u16* ubuf   = (u16*)(ws + 29400576);   // 25600000 B  [N,256] bf16
  int* flag   = (int*)(ws + 55000576);   // 4 B

  // dtype detect (probe x)
  detect_kernel<<<1, 64, 0, stream>>>((const u16*)x, flag);

  // CSR build (incoming edges grouped by dst)
  hipMemsetAsync(deg, 0, (size_t)N * 4, stream);
  hist_kernel<<<(E + 255) / 256, 256, 0, stream>>>(dst, E, deg);
  scan_kernel<<<1, 1024, 0, stream>>>(deg, rowptr, cursor, N);
  fill_kernel<<<(E + 255) / 256, 256, 0, stream>>>(src, dst, E, cursor, colarr);

  // layer 1: t = [x'@W1e | c'@W1c]  (x'/c' = missing-value replaced, native dtype)
  simple_gemm<true, true, false, false><<<N, 128, 0, stream>>>(
      x, 256, me_x, W1e, 256, tbuf, 256, 0, 128, nullptr, flag);
  simple_gemm<true, true, false, false><<<N, 128, 0, stream>>>(
      c, 128, me_c, W1c, 128, tbuf, 256, 128, 128, nullptr, flag);
  agg_kernel<<<(N + 3) / 4, 256, 0, stream>>>(tbuf, rowptr, colarr,
      e1e, e1c, b1e, b1c, ubuf, N, flag);

  // layer 2
  simple_gemm<false, false, false, false><<<N, 128, 0, stream>>>(
      ubuf, 256, nullptr, W2e, 128, tbuf, 256, 0, 128, nullptr, flag);
  simple_gemm<false, false, false, false><<<N, 128, 0, stream>>>(
      (const u16*)ubuf + 128, 256, nullptr, W2c, 128, tbuf, 256, 128, 128, nullptr, flag);
  agg_kernel<<<(N + 3) / 4, 256, 0, stream>>>(tbuf, rowptr, colarr,
      e2e, e2c, b2e, b2c, ubuf, N, flag);

  // head: out = lrelu(u @ Wm + bm) -> d_out[0 : N*8]  (FLOAT32 output)
  simple_gemm<false, false, true, true><<<N, 128, 0, stream>>>(
      ubuf, 256, nullptr, Wm, 256, d_out, 8, 0, 8, bm, flag);

  // central MLP -> d_out[N*8 : N*8 + Cn*8]  (FLOAT32)
  mlp_kernel<<<Cn, 128, 0, stream>>>((const float*)d_out, cidx,
      Wp1, bp1, Wp2, bp2, (float*)d_out + (size_t)N * 8, flag);
}

// Round 5
// 501.131 us; speedup vs baseline: 2.8107x; 2.8107x over previous
//
#include <hip/hip_runtime.h>

typedef unsigned short u16;
typedef __attribute__((ext_vector_type(8))) short short8;
typedef __attribute__((ext_vector_type(4))) float floatx4;

__device__ __forceinline__ float b2f(unsigned int ubits) {
  union { unsigned int i; float f; } cv; cv.i = ubits << 16; return cv.f;
}
__device__ __forceinline__ u16 f2b(float f) {
  unsigned int u = __builtin_bit_cast(unsigned int, f);
  u += 0x7fffu + ((u >> 16) & 1u);   // RNE
  return (u16)(u >> 16);
}
__device__ __forceinline__ float lrelu(float v) { return v > 0.f ? v : 0.2f * v; }
// read float from buffer whose dtype is decided at runtime (bf16 vs f32)
__device__ __forceinline__ float rdf(bool isbf, const void* p, int idx) {
  return isbf ? b2f((unsigned int)((const u16*)p)[idx]) : ((const float*)p)[idx];
}

// ---------------- dtype detection: 1 = bf16, 0 = f32 ----------------
__global__ void detect_kernel(const u16* __restrict__ probe, int* __restrict__ flag) {
  if (threadIdx.x == 0 && blockIdx.x == 0) {
    int cnt = 0;
    for (int i = 0; i < 256; i++) {
      unsigned int u = probe[i];
      unsigned int e = (u >> 7) & 0xFFu;
      if ((u & 0x7fffu) == 0 || (e >= 60 && e <= 191)) cnt++;
    }
    *flag = (cnt >= 240) ? 1 : 0;
  }
}

// ---------------- CSR build ----------------
__global__ __launch_bounds__(256) void hist_kernel(const int* __restrict__ dst, int E,
                                                   int* __restrict__ deg) {
  int i = blockIdx.x * 256 + threadIdx.x;
  if (i < E) atomicAdd(deg + dst[i], 1);
}

__global__ __launch_bounds__(1024) void scan_kernel(const int* __restrict__ deg,
                                                    int* __restrict__ rowptr,
                                                    int* __restrict__ cursor, int n) {
  __shared__ int wsum[16];
  __shared__ int carry_s;
  int tid = threadIdx.x, lane = tid & 63, wid = tid >> 6;
  if (tid == 0) carry_s = 0;
  __syncthreads();
  for (int base = 0; base < n; base += 4096) {
    int i0 = base + tid * 4;
    int v0 = 0, v1 = 0, v2 = 0, v3 = 0;
    if (i0 + 3 < n) {
      int4 t4 = *(const int4*)(deg + i0);
      v0 = t4.x; v1 = t4.y; v2 = t4.z; v3 = t4.w;
    } else {
      if (i0 < n) v0 = deg[i0];
      if (i0 + 1 < n) v1 = deg[i0 + 1];
      if (i0 + 2 < n) v2 = deg[i0 + 2];
      if (i0 + 3 < n) v3 = deg[i0 + 3];
    }
    int local = v0 + v1 + v2 + v3;
    int incl = local;
#pragma unroll
    for (int off = 1; off < 64; off <<= 1) {
      int t = __shfl_up(incl, off, 64);
      if (lane >= off) incl += t;
    }
    if (lane == 63) wsum[wid] = incl;
    __syncthreads();
    int woff = 0;
    for (int w = 0; w < wid; w++) woff += wsum[w];
    int run = carry_s + woff + incl - local;
    if (i0 < n)     { rowptr[i0] = run;     cursor[i0] = run; }     run += v0;
    if (i0 + 1 < n) { rowptr[i0 + 1] = run; cursor[i0 + 1] = run; } run += v1;
    if (i0 + 2 < n) { rowptr[i0 + 2] = run; cursor[i0 + 2] = run; } run += v2;
    if (i0 + 3 < n) { rowptr[i0 + 3] = run; cursor[i0 + 3] = run; }
    __syncthreads();
    if (tid == 1023) carry_s = carry_s + woff + incl;
    __syncthreads();
  }
  if (tid == 0) rowptr[n] = carry_s;
}

__global__ __launch_bounds__(256) void fill_kernel(const int* __restrict__ src,
                                                   const int* __restrict__ dst, int E,
                                                   int* __restrict__ cursor,
                                                   int* __restrict__ colarr) {
  int i = blockIdx.x * 256 + threadIdx.x;
  if (i < E) {
    int p = atomicAdd(cursor + dst[i], 1);
    colarr[p] = src[i];
  }
}

// -------- weight transpose: W[K][N] (native dtype) -> Wt[Npad][K] bf16 (zero-padded) --------
__global__ __launch_bounds__(256) void transpose_w(const void* __restrict__ W, u16* __restrict__ Wt,
                                                   int K, int N, int Npad,
                                                   const int* __restrict__ flagp) {
  bool isbf = (*flagp != 0);
  int idx = blockIdx.x * 256 + threadIdx.x;
  if (idx >= Npad * K) return;
  int n = idx / K;
  int k = idx - n * K;
  Wt[idx] = (n < N) ? f2b(rdf(isbf, W, k * N + n)) : (u16)0;
}

// ---------------- MFMA GEMM:  C[M x ncols] = A[M x K] @ B  (B given as Bt[n][k] bf16) ----------
// RAW_A: A dtype decided at runtime (bf16 vs f32). HAS_ME: replace exact-zero with me[k].
// OUT_F32: store float32 (head), else bf16.
template <int NSUB, bool RAW_A, bool HAS_ME, bool HAS_EPI, bool OUT_F32>
__global__ __launch_bounds__(256) void mfma_gemm(
    const void* __restrict__ Av, int lda,
    const void* __restrict__ me,
    const u16* __restrict__ Bt, int K, int M,
    void* __restrict__ C, int ldc, int colofs, int ncols,
    const void* __restrict__ bias, const int* __restrict__ flagp) {
  bool isbf = (*flagp != 0);
  int wid = threadIdx.x >> 6;
  int lane = threadIdx.x & 63;
  int l15 = lane & 15;
  int q = lane >> 4;
  int row0 = blockIdx.x * 128 + wid * 32;

  floatx4 acc[2][NSUB];
#pragma unroll
  for (int m = 0; m < 2; m++)
#pragma unroll
    for (int n = 0; n < NSUB; n++) acc[m][n] = (floatx4){0.f, 0.f, 0.f, 0.f};

  for (int k0 = 0; k0 < K; k0 += 32) {
    short8 a[2];
#pragma unroll
    for (int m = 0; m < 2; m++) {
      int r = row0 + m * 16 + l15;
      if (r >= M) r = M - 1;
      if (!RAW_A || isbf) {
        const u16* A = (const u16*)Av;
        a[m] = *(const short8*)(A + (long)r * lda + k0 + q * 8);
        if (HAS_ME) {
#pragma unroll
          for (int j = 0; j < 8; j++) {
            if (((u16)a[m][j] & 0x7fffu) == 0)
              a[m][j] = (short)f2b(rdf(isbf, me, k0 + q * 8 + j));
          }
        }
      } else {
        const float* A = (const float*)Av;
        const uint4* p = (const uint4*)(A + (long)r * lda + k0 + q * 8);
        uint4 w0 = p[0];
        uint4 w1 = p[1];
        unsigned int ww[8] = {w0.x, w0.y, w0.z, w0.w, w1.x, w1.y, w1.z, w1.w};
#pragma unroll
        for (int j = 0; j < 8; j++) {
          if (HAS_ME && (ww[j] & 0x7fffffffu) == 0)
            a[m][j] = (short)f2b(((const float*)me)[k0 + q * 8 + j]);
          else
            a[m][j] = (short)f2b(__builtin_bit_cast(float, ww[j]));
        }
      }
    }
#pragma unroll
    for (int n = 0; n < NSUB; n++) {
      short8 b = *(const short8*)(Bt + (n * 16 + l15) * K + k0 + q * 8);
#pragma unroll
      for (int m = 0; m < 2; m++)
        acc[m][n] = __builtin_amdgcn_mfma_f32_16x16x32_bf16(a[m], b, acc[m][n], 0, 0, 0);
    }
  }

#pragma unroll
  for (int m = 0; m < 2; m++)
#pragma unroll
    for (int n = 0; n < NSUB; n++)
#pragma unroll
      for (int r = 0; r < 4; r++) {
        int row = row0 + m * 16 + q * 4 + r;
        int col = n * 16 + l15;
        if (row < M && col < ncols) {
          float v = acc[m][n][r];
          if (HAS_EPI) {
            v += rdf(isbf, bias, col);
            v = lrelu(v);
          }
          if (OUT_F32)
            ((float*)C)[(long)row * ldc + colofs + col] = v;
          else
            ((u16*)C)[(long)row * ldc + colofs + col] = f2b(v);
        }
      }
}

// ---------------- aggregation + GIN epilogue (one wave per node, 256 feats = [e|c], bf16) --------
__global__ __launch_bounds__(256) void agg_kernel(
    const u16* __restrict__ t, const int* __restrict__ rowptr, const int* __restrict__ colarr,
    const void* __restrict__ epsE, const void* __restrict__ epsC,
    const void* __restrict__ bE, const void* __restrict__ bC,
    u16* __restrict__ u, int N, const int* __restrict__ flagp) {
  int node = blockIdx.x * 4 + (threadIdx.x >> 6);
  if (node >= N) return;
  bool isbf = (*flagp != 0);
  int lane = threadIdx.x & 63;
  int f0 = lane << 2;  // 4 features per lane
  const u16* tb = t + f0;
  float a0 = 0.f, a1 = 0.f, a2 = 0.f, a3 = 0.f;
  int e = rowptr[node], e1 = rowptr[node + 1];
  for (; e + 4 <= e1; e += 4) {
    int c0 = colarr[e], c1 = colarr[e + 1], c2 = colarr[e + 2], c3 = colarr[e + 3];
    uint2 p0 = *(const uint2*)(tb + ((long)c0 << 8));
    uint2 p1 = *(const uint2*)(tb + ((long)c1 << 8));
    uint2 p2 = *(const uint2*)(tb + ((long)c2 << 8));
    uint2 p3 = *(const uint2*)(tb + ((long)c3 << 8));
    a0 += b2f(p0.x & 0xffffu); a1 += b2f(p0.x >> 16); a2 += b2f(p0.y & 0xffffu); a3 += b2f(p0.y >> 16);
    a0 += b2f(p1.x & 0xffffu); a1 += b2f(p1.x >> 16); a2 += b2f(p1.y & 0xffffu); a3 += b2f(p1.y >> 16);
    a0 += b2f(p2.x & 0xffffu); a1 += b2f(p2.x >> 16); a2 += b2f(p2.y & 0xffffu); a3 += b2f(p2.y >> 16);
    a0 += b2f(p3.x & 0xffffu); a1 += b2f(p3.x >> 16); a2 += b2f(p3.y & 0xffffu); a3 += b2f(p3.y >> 16);
  }
  for (; e < e1; e++) {
    int c = colarr[e];
    uint2 p = *(const uint2*)(tb + ((long)c << 8));
    a0 += b2f(p.x & 0xffffu); a1 += b2f(p.x >> 16); a2 += b2f(p.y & 0xffffu); a3 += b2f(p.y >> 16);
  }
  // self term: (1+eps)*t_i + self-loop t_i = (2+eps)*t_i
  uint2 ps = *(const uint2*)(tb + ((long)node << 8));
  bool isE = (lane < 32);
  float eps2 = 2.0f + rdf(isbf, isE ? epsE : epsC, 0);
  const void* bp = isE ? bE : bC;
  int bi = isE ? f0 : (f0 - 128);
  float bb0 = rdf(isbf, bp, bi);
  float bb1 = rdf(isbf, bp, bi + 1);
  float bb2 = rdf(isbf, bp, bi + 2);
  float bb3 = rdf(isbf, bp, bi + 3);
  a0 = lrelu(a0 + eps2 * b2f(ps.x & 0xffffu) + bb0);
  a1 = lrelu(a1 + eps2 * b2f(ps.x >> 16)     + bb1);
  a2 = lrelu(a2 + eps2 * b2f(ps.y & 0xffffu) + bb2);
  a3 = lrelu(a3 + eps2 * b2f(ps.y >> 16)     + bb3);
  unsigned int lo = ((unsigned int)f2b(a1) << 16) | f2b(a0);
  unsigned int hi = ((unsigned int)f2b(a3) << 16) | f2b(a2);
  *(uint2*)(u + ((long)node << 8) + f0) = make_uint2(lo, hi);
}

// ---------------- central-node MLP (f32 in, f32 out) ----------------
__global__ __launch_bounds__(128) void mlp_kernel(
    const float* __restrict__ outbuf, const int* __restrict__ central,
    const void* __restrict__ Wp1, const void* __restrict__ bp1,
    const void* __restrict__ Wp2, const void* __restrict__ bp2,
    float* __restrict__ logits, const int* __restrict__ flagp) {
  __shared__ float h1[128];
  __shared__ float o[8];
  bool isbf = (*flagp != 0);
  int b = blockIdx.x, tid = threadIdx.x;
  int node = central[b];
  if (tid < 8) o[tid] = outbuf[node * 8 + tid];
  __syncthreads();
  float s = rdf(isbf, bp1, tid);
#pragma unroll
  for (int k = 0; k < 8; k++) s += o[k] * rdf(isbf, Wp1, k * 128 + tid);
  h1[tid] = fmaxf(s, 0.f);
  __syncthreads();
  if (tid < 8) {
    float s2 = rdf(isbf, bp2, tid);
    for (int k = 0; k < 128; k++) s2 += h1[k] * rdf(isbf, Wp2, k * 8 + tid);
    logits[b * 8 + tid] = s2;
  }
}

extern "C" void kernel_launch(void* const* d_in, const int* in_sizes, int n_in,
                              void* d_out, int out_size, void* d_ws, size_t ws_size,
                              hipStream_t stream) {
  const void* x    = d_in[0];
  const void* c    = d_in[1];
  const int* eidx  = (const int*)d_in[2];
  const int* cidx  = (const int*)d_in[3];
  const void* me_x = d_in[4];
  const void* me_c = d_in[5];
  const void* W1e  = d_in[6];
  const void* b1e  = d_in[7];
  const void* e1e  = d_in[8];
  const void* W2e  = d_in[9];
  const void* b2e  = d_in[10];
  const void* e2e  = d_in[11];
  const void* W1c  = d_in[12];
  const void* b1c  = d_in[13];
  const void* e1c  = d_in[14];
  const void* W2c  = d_in[15];
  const void* b2c  = d_in[16];
  const void* e2c  = d_in[17];
  const void* Wm   = d_in[18];
  const void* bm   = d_in[19];
  const void* Wp1  = d_in[20];
  const void* bp1  = d_in[21];
  const void* Wp2  = d_in[22];
  const void* bp2  = d_in[23];

  const int N = in_sizes[0] / 256;   // 50000
  const int E = in_sizes[2] / 2;     // 800000
  const int Cn = in_sizes[3];        // 512
  const int* src = eidx;
  const int* dst = eidx + E;

  char* ws = (char*)d_ws;
  int* deg    = (int*)(ws + 0);          // 200000 B
  int* rowptr = (int*)(ws + 200192);     // 200004 B
  int* cursor = (int*)(ws + 400384);     // 200000 B
  int* colarr = (int*)(ws + 600576);     // 3200000 B
  u16* tbuf   = (u16*)(ws + 3800576);    // 25600000 B  [N,256] bf16
  u16* ubuf   = (u16*)(ws + 29400576);   // 25600000 B  [N,256] bf16
  u16* w1e_t  = (u16*)(ws + 55000576);   // 65536 B   [128][256] bf16
  u16* w1c_t  = (u16*)(ws + 55066112);   // 32768 B   [128][128]
  u16* w2e_t  = (u16*)(ws + 55098880);   // 32768 B
  u16* w2c_t  = (u16*)(ws + 55131648);   // 32768 B
  u16* wm_t   = (u16*)(ws + 55164416);   // 8192 B    [16][256] zero-padded
  int* flag   = (int*)(ws + 55172608);   // 4 B

  // dtype detect (probe x)
  detect_kernel<<<1, 64, 0, stream>>>((const u16*)x, flag);

  // CSR build (incoming edges grouped by dst)
  hipMemsetAsync(deg, 0, (size_t)N * 4, stream);
  hist_kernel<<<(E + 255) / 256, 256, 0, stream>>>(dst, E, deg);
  scan_kernel<<<1, 1024, 0, stream>>>(deg, rowptr, cursor, N);
  fill_kernel<<<(E + 255) / 256, 256, 0, stream>>>(src, dst, E, cursor, colarr);

  // weight transposes (native dtype -> bf16 [n][k])
  transpose_w<<<(128 * 256 + 255) / 256, 256, 0, stream>>>(W1e, w1e_t, 256, 128, 128, flag);
  transpose_w<<<(128 * 128 + 255) / 256, 256, 0, stream>>>(W1c, w1c_t, 128, 128, 128, flag);
  transpose_w<<<(128 * 128 + 255) / 256, 256, 0, stream>>>(W2e, w2e_t, 128, 128, 128, flag);
  transpose_w<<<(128 * 128 + 255) / 256, 256, 0, stream>>>(W2c, w2c_t, 128, 128, 128, flag);
  transpose_w<<<(16 * 256 + 255) / 256, 256, 0, stream>>>(Wm, wm_t, 256, 8, 16, flag);

  int gblocks = (N + 127) / 128;
  // layer 1: t = [x'@W1e | c'@W1c]  (missing-value replaced; A dtype runtime-decided)
  mfma_gemm<8, true, true, false, false><<<gblocks, 256, 0, stream>>>(
      x, 256, me_x, w1e_t, 256, N, tbuf, 256, 0, 128, nullptr, flag);
  mfma_gemm<8, true, true, false, false><<<gblocks, 256, 0, stream>>>(
      c, 128, me_c, w1c_t, 128, N, tbuf, 256, 128, 128, nullptr, flag);
  agg_kernel<<<(N + 3) / 4, 256, 0, stream>>>(tbuf, rowptr, colarr,
      e1e, e1c, b1e, b1c, ubuf, N, flag);

  // layer 2
  mfma_gemm<8, false, false, false, false><<<gblocks, 256, 0, stream>>>(
      ubuf, 256, nullptr, w2e_t, 128, N, tbuf, 256, 0, 128, nullptr, flag);
  mfma_gemm<8, false, false, false, false><<<gblocks, 256, 0, stream>>>(
      (const u16*)ubuf + 128, 256, nullptr, w2c_t, 128, N, tbuf, 256, 128, 128, nullptr, flag);
  agg_kernel<<<(N + 3) / 4, 256, 0, stream>>>(tbuf, rowptr, colarr,
      e2e, e2c, b2e, b2c, ubuf, N, flag);

  // head: out = lrelu(u @ Wm + bm) -> d_out[0 : N*8]  (f32 out)
  mfma_gemm<1, false, false, true, true><<<gblocks, 256, 0, stream>>>(
      ubuf, 256, nullptr, wm_t, 256, N, d_out, 8, 0, 8, bm, flag);

  // central MLP -> d_out[N*8 : N*8 + Cn*8]  (f32)
  mlp_kernel<<<Cn, 128, 0, stream>>>((const float*)d_out, cidx,
      Wp1, bp1, Wp2, bp2, (float*)d_out + (size_t)N * 8, flag);
}

// Round 6
// 488.660 us; speedup vs baseline: 2.8824x; 1.0255x over previous
//
#include <hip/hip_runtime.h>

typedef unsigned short u16;
typedef __attribute__((ext_vector_type(8))) short short8;
typedef __attribute__((ext_vector_type(4))) float floatx4;

__device__ __forceinline__ float b2f(unsigned int ubits) {
  union { unsigned int i; float f; } cv; cv.i = ubits << 16; return cv.f;
}
__device__ __forceinline__ float hi2f(unsigned int u) {
  union { unsigned int i; float f; } cv; cv.i = u & 0xffff0000u; return cv.f;
}
__device__ __forceinline__ float lo2f(unsigned int u) {
  union { unsigned int i; float f; } cv; cv.i = u << 16; return cv.f;
}
__device__ __forceinline__ u16 f2b(float f) {
  unsigned int u = __builtin_bit_cast(unsigned int, f);
  u += 0x7fffu + ((u >> 16) & 1u);   // RNE
  return (u16)(u >> 16);
}
__device__ __forceinline__ float lrelu(float v) { return v > 0.f ? v : 0.2f * v; }
// read float from buffer whose dtype is decided at runtime (bf16 vs f32)
__device__ __forceinline__ float rdf(bool isbf, const void* p, int idx) {
  return isbf ? b2f((unsigned int)((const u16*)p)[idx]) : ((const float*)p)[idx];
}

// ---------------- dtype detection: 1 = bf16, 0 = f32 ----------------
__global__ void detect_kernel(const u16* __restrict__ probe, int* __restrict__ flag) {
  int lane = threadIdx.x;  // 64
  int cnt = 0;
  for (int i = lane; i < 256; i += 64) {
    unsigned int u = probe[i];
    unsigned int e = (u >> 7) & 0xFFu;
    if ((u & 0x7fffu) == 0 || (e >= 60 && e <= 191)) cnt++;
  }
#pragma unroll
  for (int off = 32; off; off >>= 1) cnt += __shfl_down(cnt, off, 64);
  if (lane == 0) *flag = (cnt >= 240) ? 1 : 0;
}

// ---------------- CSR build ----------------
__global__ __launch_bounds__(256) void hist_kernel(const int* __restrict__ dst, int E,
                                                   int* __restrict__ deg) {
  int i = blockIdx.x * 256 + threadIdx.x;
  if (i < E) atomicAdd(deg + dst[i], 1);
}

#define SCB 1024  // nodes per scan block (256 thr x 4)

__global__ __launch_bounds__(256) void scan_phaseA(const int* __restrict__ deg,
                                                   int* __restrict__ bsum, int n) {
  int i0 = blockIdx.x * SCB + threadIdx.x * 4;
  int s = 0;
  if (i0 + 3 < n) {
    int4 v = *(const int4*)(deg + i0);
    s = v.x + v.y + v.z + v.w;
  } else {
    for (int j = 0; j < 4; j++) if (i0 + j < n) s += deg[i0 + j];
  }
#pragma unroll
  for (int off = 32; off; off >>= 1) s += __shfl_down(s, off, 64);
  __shared__ int ws4[4];
  int lane = threadIdx.x & 63, wid = threadIdx.x >> 6;
  if (lane == 0) ws4[wid] = s;
  __syncthreads();
  if (threadIdx.x == 0) bsum[blockIdx.x] = ws4[0] + ws4[1] + ws4[2] + ws4[3];
}

__global__ void scan_phaseB(const int* __restrict__ bsum, int* __restrict__ boff,
                            int PB, int* __restrict__ rowptr, int n) {
  int lane = threadIdx.x;  // 64, PB <= 64
  int v = (lane < PB) ? bsum[lane] : 0;
  int incl = v;
#pragma unroll
  for (int off = 1; off < 64; off <<= 1) {
    int t = __shfl_up(incl, off, 64);
    if (lane >= off) incl += t;
  }
  if (lane < PB) boff[lane] = incl - v;
  if (lane == 63) rowptr[n] = incl;
}

__global__ __launch_bounds__(256) void scan_phaseC(const int* __restrict__ deg,
                                                   const int* __restrict__ boff,
                                                   int* __restrict__ rowptr,
                                                   int* __restrict__ cursor, int n) {
  int i0 = blockIdx.x * SCB + threadIdx.x * 4;
  int v0 = 0, v1 = 0, v2 = 0, v3 = 0;
  if (i0 + 3 < n) {
    int4 v = *(const int4*)(deg + i0);
    v0 = v.x; v1 = v.y; v2 = v.z; v3 = v.w;
  } else {
    if (i0 < n) v0 = deg[i0];
    if (i0 + 1 < n) v1 = deg[i0 + 1];
    if (i0 + 2 < n) v2 = deg[i0 + 2];
    if (i0 + 3 < n) v3 = deg[i0 + 3];
  }
  int local = v0 + v1 + v2 + v3;
  int lane = threadIdx.x & 63, wid = threadIdx.x >> 6;
  int incl = local;
#pragma unroll
  for (int off = 1; off < 64; off <<= 1) {
    int t = __shfl_up(incl, off, 64);
    if (lane >= off) incl += t;
  }
  __shared__ int ws4[4];
  if (lane == 63) ws4[wid] = incl;
  __syncthreads();
  int woff = 0;
  for (int w = 0; w < wid; w++) woff += ws4[w];
  int run = boff[blockIdx.x] + woff + incl - local;
  if (i0 < n)     { rowptr[i0] = run;     cursor[i0] = run; }     run += v0;
  if (i0 + 1 < n) { rowptr[i0 + 1] = run; cursor[i0 + 1] = run; } run += v1;
  if (i0 + 2 < n) { rowptr[i0 + 2] = run; cursor[i0 + 2] = run; } run += v2;
  if (i0 + 3 < n) { rowptr[i0 + 3] = run; cursor[i0 + 3] = run; }
}

__global__ __launch_bounds__(256) void fill_kernel(const int* __restrict__ src,
                                                   const int* __restrict__ dst, int E,
                                                   int* __restrict__ cursor,
                                                   int* __restrict__ colarr) {
  int i = blockIdx.x * 256 + threadIdx.x;
  if (i < E) {
    int p = atomicAdd(cursor + dst[i], 1);
    colarr[p] = src[i];
  }
}

// -------- all weight transposes in one kernel: W[K][N] (native) -> Wt[Npad][K] bf16 --------
struct TWDesc {
  const void* W[5];
  int K[5];
  int Nc[5];
  int base[6];  // u16 offsets into wt_all
};

__global__ __launch_bounds__(256) void transpose_all(TWDesc d, u16* __restrict__ out,
                                                     const int* __restrict__ flagp) {
  bool isbf = (*flagp != 0);
  int idx = blockIdx.x * 256 + threadIdx.x;
  if (idx >= d.base[5]) return;
  int s = 0;
  while (idx >= d.base[s + 1]) s++;
  int local = idx - d.base[s];
  int K = d.K[s], Nc = d.Nc[s];
  int nn = local / K;
  int k = local - nn * K;
  out[idx] = (nn < Nc) ? f2b(rdf(isbf, d.W[s], k * Nc + nn)) : (u16)0;
}

// ---------------- MFMA GEMM:  C[M x ncols] = A[M x K] @ B  (B given as Bt[n][k] bf16) ----------
// 64 rows per block (4 waves x 16 rows). RAW_A: A dtype runtime-decided. HAS_ME: zero->me[k].
template <int NSUB, bool RAW_A, bool HAS_ME, bool HAS_EPI, bool OUT_F32>
__global__ __launch_bounds__(256) void mfma_gemm(
    const void* __restrict__ Av, int lda,
    const void* __restrict__ me,
    const u16* __restrict__ Bt, int K, int M,
    void* __restrict__ C, int ldc, int colofs, int ncols,
    const void* __restrict__ bias, const int* __restrict__ flagp) {
  bool isbf = (*flagp != 0);
  int wid = threadIdx.x >> 6;
  int lane = threadIdx.x & 63;
  int l15 = lane & 15;
  int q = lane >> 4;
  int row0 = blockIdx.x * 64 + wid * 16;

  floatx4 acc[NSUB];
#pragma unroll
  for (int n = 0; n < NSUB; n++) acc[n] = (floatx4){0.f, 0.f, 0.f, 0.f};

  int r = row0 + l15;
  if (r >= M) r = M - 1;

  for (int k0 = 0; k0 < K; k0 += 32) {
    short8 a;
    if (!RAW_A || isbf) {
      const u16* A = (const u16*)Av;
      a = *(const short8*)(A + (long)r * lda + k0 + q * 8);
      if (HAS_ME) {
#pragma unroll
        for (int j = 0; j < 8; j++) {
          if (((u16)a[j] & 0x7fffu) == 0)
            a[j] = (short)f2b(rdf(isbf, me, k0 + q * 8 + j));
        }
      }
    } else {
      const float* A = (const float*)Av;
      const uint4* p = (const uint4*)(A + (long)r * lda + k0 + q * 8);
      uint4 w0 = p[0];
      uint4 w1 = p[1];
      unsigned int ww[8] = {w0.x, w0.y, w0.z, w0.w, w1.x, w1.y, w1.z, w1.w};
#pragma unroll
      for (int j = 0; j < 8; j++) {
        if (HAS_ME && (ww[j] & 0x7fffffffu) == 0)
          a[j] = (short)f2b(((const float*)me)[k0 + q * 8 + j]);
        else
          a[j] = (short)f2b(__builtin_bit_cast(float, ww[j]));
      }
    }
#pragma unroll
    for (int n = 0; n < NSUB; n++) {
      short8 b = *(const short8*)(Bt + (n * 16 + l15) * K + k0 + q * 8);
      acc[n] = __builtin_amdgcn_mfma_f32_16x16x32_bf16(a, b, acc[n], 0, 0, 0);
    }
  }

#pragma unroll
  for (int n = 0; n < NSUB; n++)
#pragma unroll
    for (int rr = 0; rr < 4; rr++) {
      int row = row0 + q * 4 + rr;
      int col = n * 16 + l15;
      if (row < M && col < ncols) {
        float v = acc[n][rr];
        if (HAS_EPI) {
          v += rdf(isbf, bias, col);
          v = lrelu(v);
        }
        if (OUT_F32)
          ((float*)C)[(long)row * ldc + colofs + col] = v;
        else
          ((u16*)C)[(long)row * ldc + colofs + col] = f2b(v);
      }
    }
}

// ------- aggregation + GIN epilogue (half-wave per node, 8 feats/lane via uint4, bf16) -------
__global__ __launch_bounds__(256) void agg_kernel(
    const u16* __restrict__ t, const int* __restrict__ rowptr, const int* __restrict__ colarr,
    const void* __restrict__ epsE, const void* __restrict__ epsC,
    const void* __restrict__ bE, const void* __restrict__ bC,
    u16* __restrict__ u, int N, const int* __restrict__ flagp) {
  int node = blockIdx.x * 8 + (threadIdx.x >> 5);
  if (node >= N) return;
  bool isbf = (*flagp != 0);
  int lane = threadIdx.x & 31;
  int f0 = lane << 3;  // 8 features per lane
  const u16* tb = t + f0;
  float a0 = 0.f, a1 = 0.f, a2 = 0.f, a3 = 0.f, a4 = 0.f, a5 = 0.f, a6 = 0.f, a7 = 0.f;
  int e = rowptr[node], e1 = rowptr[node + 1];
#define ACC8(p)                                                   \
  a0 += lo2f(p.x); a1 += hi2f(p.x); a2 += lo2f(p.y); a3 += hi2f(p.y); \
  a4 += lo2f(p.z); a5 += hi2f(p.z); a6 += lo2f(p.w); a7 += hi2f(p.w);
  for (; e + 4 <= e1; e += 4) {
    int c0 = colarr[e], c1 = colarr[e + 1], c2 = colarr[e + 2], c3 = colarr[e + 3];
    uint4 p0 = *(const uint4*)(tb + ((long)c0 << 8));
    uint4 p1 = *(const uint4*)(tb + ((long)c1 << 8));
    uint4 p2 = *(const uint4*)(tb + ((long)c2 << 8));
    uint4 p3 = *(const uint4*)(tb + ((long)c3 << 8));
    ACC8(p0) ACC8(p1) ACC8(p2) ACC8(p3)
  }
  for (; e < e1; e++) {
    int c = colarr[e];
    uint4 p = *(const uint4*)(tb + ((long)c << 8));
    ACC8(p)
  }
#undef ACC8
  // self term: (1+eps)*t_i + self-loop t_i = (2+eps)*t_i
  uint4 ps = *(const uint4*)(tb + ((long)node << 8));
  bool isE = (f0 < 128);
  float eps2 = 2.0f + rdf(isbf, isE ? epsE : epsC, 0);
  const void* bp = isE ? bE : bC;
  int bi = isE ? f0 : (f0 - 128);
  a0 = lrelu(a0 + eps2 * lo2f(ps.x) + rdf(isbf, bp, bi + 0));
  a1 = lrelu(a1 + eps2 * hi2f(ps.x) + rdf(isbf, bp, bi + 1));
  a2 = lrelu(a2 + eps2 * lo2f(ps.y) + rdf(isbf, bp, bi + 2));
  a3 = lrelu(a3 + eps2 * hi2f(ps.y) + rdf(isbf, bp, bi + 3));
  a4 = lrelu(a4 + eps2 * lo2f(ps.z) + rdf(isbf, bp, bi + 4));
  a5 = lrelu(a5 + eps2 * hi2f(ps.z) + rdf(isbf, bp, bi + 5));
  a6 = lrelu(a6 + eps2 * lo2f(ps.w) + rdf(isbf, bp, bi + 6));
  a7 = lrelu(a7 + eps2 * hi2f(ps.w) + rdf(isbf, bp, bi + 7));
  uint4 o;
  o.x = ((unsigned int)f2b(a1) << 16) | f2b(a0);
  o.y = ((unsigned int)f2b(a3) << 16) | f2b(a2);
  o.z = ((unsigned int)f2b(a5) << 16) | f2b(a4);
  o.w = ((unsigned int)f2b(a7) << 16) | f2b(a6);
  *(uint4*)(u + ((long)node << 8) + f0) = o;
}

// ---------------- central-node MLP (f32 in, f32 out) ----------------
__global__ __launch_bounds__(128) void mlp_kernel(
    const float* __restrict__ outbuf, const int* __restrict__ central,
    const void* __restrict__ Wp1, const void* __restrict__ bp1,
    const void* __restrict__ Wp2, const void* __restrict__ bp2,
    float* __restrict__ logits, const int* __restrict__ flagp) {
  __shared__ float h1[128];
  __shared__ float o[8];
  bool isbf = (*flagp != 0);
  int b = blockIdx.x, tid = threadIdx.x;
  int node = central[b];
  if (tid < 8) o[tid] = outbuf[node * 8 + tid];
  __syncthreads();
  float s = rdf(isbf, bp1, tid);
#pragma unroll
  for (int k = 0; k < 8; k++) s += o[k] * rdf(isbf, Wp1, k * 128 + tid);
  h1[tid] = fmaxf(s, 0.f);
  __syncthreads();
  if (tid < 8) {
    float s2 = rdf(isbf, bp2, tid);
    for (int k = 0; k < 128; k++) s2 += h1[k] * rdf(isbf, Wp2, k * 8 + tid);
    logits[b * 8 + tid] = s2;
  }
}

extern "C" void kernel_launch(void* const* d_in, const int* in_sizes, int n_in,
                              void* d_out, int out_size, void* d_ws, size_t ws_size,
                              hipStream_t stream) {
  const void* x    = d_in[0];
  const void* c    = d_in[1];
  const int* eidx  = (const int*)d_in[2];
  const int* cidx  = (const int*)d_in[3];
  const void* me_x = d_in[4];
  const void* me_c = d_in[5];
  const void* W1e  = d_in[6];
  const void* b1e  = d_in[7];
  const void* e1e  = d_in[8];
  const void* W2e  = d_in[9];
  const void* b2e  = d_in[10];
  const void* e2e  = d_in[11];
  const void* W1c  = d_in[12];
  const void* b1c  = d_in[13];
  const void* e1c  = d_in[14];
  const void* W2c  = d_in[15];
  const void* b2c  = d_in[16];
  const void* e2c  = d_in[17];
  const void* Wm   = d_in[18];
  const void* bm   = d_in[19];
  const void* Wp1  = d_in[20];
  const void* bp1  = d_in[21];
  const void* Wp2  = d_in[22];
  const void* bp2  = d_in[23];

  const int N = in_sizes[0] / 256;   // 50000
  const int E = in_sizes[2] / 2;     // 800000
  const int Cn = in_sizes[3];        // 512
  const int* src = eidx;
  const int* dst = eidx + E;

  char* ws = (char*)d_ws;
  int* deg    = (int*)(ws + 0);          // 200000 B
  int* rowptr = (int*)(ws + 200192);     // 200004 B
  int* cursor = (int*)(ws + 400384);     // 200000 B
  int* colarr = (int*)(ws + 600576);     // 3200000 B
  u16* tbuf   = (u16*)(ws + 3800576);    // 25600000 B  [N,256] bf16
  u16* ubuf   = (u16*)(ws + 29400576);   // 25600000 B  [N,256] bf16
  u16* wt_all = (u16*)(ws + 55000576);   // 172032 B: all transposed weights, bf16
  int* flag   = (int*)(ws + 55172608);   // 4 B
  int* bsum   = (int*)(ws + 55172864);   // 256 B
  int* boff   = (int*)(ws + 55173120);   // 256 B

  u16* w1e_t = wt_all + 0;       // [128][256]
  u16* w1c_t = wt_all + 32768;   // [128][128]
  u16* w2e_t = wt_all + 49152;   // [128][128]
  u16* w2c_t = wt_all + 65536;   // [128][128]
  u16* wm_t  = wt_all + 81920;   // [16][256]

  // dtype detect (probe x)
  detect_kernel<<<1, 64, 0, stream>>>((const u16*)x, flag);

  // CSR build (incoming edges grouped by dst)
  hipMemsetAsync(deg, 0, (size_t)N * 4, stream);
  hist_kernel<<<(E + 255) / 256, 256, 0, stream>>>(dst, E, deg);
  int PB = (N + SCB - 1) / SCB;  // 49 (<=64 required)
  scan_phaseA<<<PB, 256, 0, stream>>>(deg, bsum, N);
  scan_phaseB<<<1, 64, 0, stream>>>(bsum, boff, PB, rowptr, N);
  scan_phaseC<<<PB, 256, 0, stream>>>(deg, boff, rowptr, cursor, N);
  fill_kernel<<<(E + 255) / 256, 256, 0, stream>>>(src, dst, E, cursor, colarr);

  // all weight transposes (native dtype -> bf16 [n][k]) in one launch
  TWDesc td;
  td.W[0] = W1e; td.K[0] = 256; td.Nc[0] = 128;
  td.W[1] = W1c; td.K[1] = 128; td.Nc[1] = 128;
  td.W[2] = W2e; td.K[2] = 128; td.Nc[2] = 128;
  td.W[3] = W2c; td.K[3] = 128; td.Nc[3] = 128;
  td.W[4] = Wm;  td.K[4] = 256; td.Nc[4] = 8;
  td.base[0] = 0; td.base[1] = 32768; td.base[2] = 49152;
  td.base[3] = 65536; td.base[4] = 81920; td.base[5] = 86016;
  transpose_all<<<(86016 + 255) / 256, 256, 0, stream>>>(td, wt_all, flag);

  int gb = (N + 63) / 64;  // 782
  // layer 1: t = [x'@W1e | c'@W1c]  (missing-value replaced; A dtype runtime-decided)
  mfma_gemm<8, true, true, false, false><<<gb, 256, 0, stream>>>(
      x, 256, me_x, w1e_t, 256, N, tbuf, 256, 0, 128, nullptr, flag);
  mfma_gemm<8, true, true, false, false><<<gb, 256, 0, stream>>>(
      c, 128, me_c, w1c_t, 128, N, tbuf, 256, 128, 128, nullptr, flag);
  agg_kernel<<<(N + 7) / 8, 256, 0, stream>>>(tbuf, rowptr, colarr,
      e1e, e1c, b1e, b1c, ubuf, N, flag);

  // layer 2
  mfma_gemm<8, false, false, false, false><<<gb, 256, 0, stream>>>(
      ubuf, 256, nullptr, w2e_t, 128, N, tbuf, 256, 0, 128, nullptr, flag);
  mfma_gemm<8, false, false, false, false><<<gb, 256, 0, stream>>>(
      (const u16*)ubuf + 128, 256, nullptr, w2c_t, 128, N, tbuf, 256, 128, 128, nullptr, flag);
  agg_kernel<<<(N + 7) / 8, 256, 0, stream>>>(tbuf, rowptr, colarr,
      e2e, e2c, b2e, b2c, ubuf, N, flag);

  // head: out = lrelu(u @ Wm + bm) -> d_out[0 : N*8]  (f32 out)
  mfma_gemm<1, false, false, true, true><<<gb, 256, 0, stream>>>(
      ubuf, 256, nullptr, wm_t, 256, N, d_out, 8, 0, 8, bm, flag);

  // central MLP -> d_out[N*8 : N*8 + Cn*8]  (f32)
  mlp_kernel<<<Cn, 128, 0, stream>>>((const float*)d_out, cidx,
      Wp1, bp1, Wp2, bp2, (float*)d_out + (size_t)N * 8, flag);
}

// Round 7
// 464.729 us; speedup vs baseline: 3.0309x; 1.0515x over previous
//
#include <hip/hip_runtime.h>

typedef unsigned short u16;
typedef __attribute__((ext_vector_type(8))) short short8;
typedef __attribute__((ext_vector_type(4))) float floatx4;

__device__ __forceinline__ float b2f(unsigned int ubits) {
  union { unsigned int i; float f; } cv; cv.i = ubits << 16; return cv.f;
}
__device__ __forceinline__ float hi2f(unsigned int u) {
  union { unsigned int i; float f; } cv; cv.i = u & 0xffff0000u; return cv.f;
}
__device__ __forceinline__ float lo2f(unsigned int u) {
  union { unsigned int i; float f; } cv; cv.i = u << 16; return cv.f;
}
__device__ __forceinline__ u16 f2b(float f) {
  unsigned int u = __builtin_bit_cast(unsigned int, f);
  u += 0x7fffu + ((u >> 16) & 1u);   // RNE
  return (u16)(u >> 16);
}
__device__ __forceinline__ float lrelu(float v) { return v > 0.f ? v : 0.2f * v; }
__device__ __forceinline__ float rdf(bool isbf, const void* p, int idx) {
  return isbf ? b2f((unsigned int)((const u16*)p)[idx]) : ((const float*)p)[idx];
}

// ---------------- init: zero deg + dtype detect (block 0) ----------------
__global__ __launch_bounds__(256) void init_kernel(int* __restrict__ deg, int n,
                                                   const u16* __restrict__ probe,
                                                   int* __restrict__ flag) {
  int i0 = (blockIdx.x * 256 + threadIdx.x) * 4;
  if (i0 + 3 < n) {
    *(int4*)(deg + i0) = make_int4(0, 0, 0, 0);
  } else {
    for (int j = 0; j < 4; j++) if (i0 + j < n) deg[i0 + j] = 0;
  }
  if (blockIdx.x == 0 && threadIdx.x < 64) {
    int lane = threadIdx.x;
    int cnt = 0;
    for (int i = lane; i < 256; i += 64) {
      unsigned int u = probe[i];
      unsigned int e = (u >> 7) & 0xFFu;
      if ((u & 0x7fffu) == 0 || (e >= 60 && e <= 191)) cnt++;
    }
#pragma unroll
    for (int off = 32; off; off >>= 1) cnt += __shfl_down(cnt, off, 64);
    if (lane == 0) *flag = (cnt >= 240) ? 1 : 0;
  }
}

// ---------------- CSR build ----------------
__global__ __launch_bounds__(256) void hist_kernel(const int* __restrict__ dst, int E,
                                                   int* __restrict__ deg) {
  int i = blockIdx.x * 256 + threadIdx.x;
  if (i < E) atomicAdd(deg + dst[i], 1);
}

#define SCB 1024  // nodes per scan block (256 thr x 4)

__global__ __launch_bounds__(256) void scan_phaseA(const int* __restrict__ deg,
                                                   int* __restrict__ bsum, int n) {
  int i0 = blockIdx.x * SCB + threadIdx.x * 4;
  int s = 0;
  if (i0 + 3 < n) {
    int4 v = *(const int4*)(deg + i0);
    s = v.x + v.y + v.z + v.w;
  } else {
    for (int j = 0; j < 4; j++) if (i0 + j < n) s += deg[i0 + j];
  }
#pragma unroll
  for (int off = 32; off; off >>= 1) s += __shfl_down(s, off, 64);
  __shared__ int ws4[4];
  int lane = threadIdx.x & 63, wid = threadIdx.x >> 6;
  if (lane == 0) ws4[wid] = s;
  __syncthreads();
  if (threadIdx.x == 0) bsum[blockIdx.x] = ws4[0] + ws4[1] + ws4[2] + ws4[3];
}

__global__ void scan_phaseB(const int* __restrict__ bsum, int* __restrict__ boff,
                            int PB, int* __restrict__ rowptr, int n) {
  int lane = threadIdx.x;  // 64, PB <= 64
  int v = (lane < PB) ? bsum[lane] : 0;
  int incl = v;
#pragma unroll
  for (int off = 1; off < 64; off <<= 1) {
    int t = __shfl_up(incl, off, 64);
    if (lane >= off) incl += t;
  }
  if (lane < PB) boff[lane] = incl - v;
  if (lane == 63) rowptr[n] = incl;
}

__global__ __launch_bounds__(256) void scan_phaseC(const int* __restrict__ deg,
                                                   const int* __restrict__ boff,
                                                   int* __restrict__ rowptr,
                                                   int* __restrict__ cursor, int n) {
  int i0 = blockIdx.x * SCB + threadIdx.x * 4;
  int v0 = 0, v1 = 0, v2 = 0, v3 = 0;
  if (i0 + 3 < n) {
    int4 v = *(const int4*)(deg + i0);
    v0 = v.x; v1 = v.y; v2 = v.z; v3 = v.w;
  } else {
    if (i0 < n) v0 = deg[i0];
    if (i0 + 1 < n) v1 = deg[i0 + 1];
    if (i0 + 2 < n) v2 = deg[i0 + 2];
    if (i0 + 3 < n) v3 = deg[i0 + 3];
  }
  int local = v0 + v1 + v2 + v3;
  int lane = threadIdx.x & 63, wid = threadIdx.x >> 6;
  int incl = local;
#pragma unroll
  for (int off = 1; off < 64; off <<= 1) {
    int t = __shfl_up(incl, off, 64);
    if (lane >= off) incl += t;
  }
  __shared__ int ws4[4];
  if (lane == 63) ws4[wid] = incl;
  __syncthreads();
  int woff = 0;
  for (int w = 0; w < wid; w++) woff += ws4[w];
  int run = boff[blockIdx.x] + woff + incl - local;
  if (i0 < n)     { rowptr[i0] = run;     cursor[i0] = run; }     run += v0;
  if (i0 + 1 < n) { rowptr[i0 + 1] = run; cursor[i0 + 1] = run; } run += v1;
  if (i0 + 2 < n) { rowptr[i0 + 2] = run; cursor[i0 + 2] = run; } run += v2;
  if (i0 + 3 < n) { rowptr[i0 + 3] = run; cursor[i0 + 3] = run; }
}

__global__ __launch_bounds__(256) void fill_kernel(const int* __restrict__ src,
                                                   const int* __restrict__ dst, int E,
                                                   int* __restrict__ cursor,
                                                   int* __restrict__ colarr) {
  int i = blockIdx.x * 256 + threadIdx.x;
  if (i < E) {
    int p = atomicAdd(cursor + dst[i], 1);
    colarr[p] = src[i];
  }
}

// -------- all weight transposes in one kernel: W[K][N] (native) -> Wt[Npad][K] bf16 --------
struct TWDesc {
  const void* W[5];
  int K[5];
  int Nc[5];
  int base[6];  // u16 offsets
};

__global__ __launch_bounds__(256) void transpose_all(TWDesc d, u16* __restrict__ out,
                                                     const int* __restrict__ flagp) {
  bool isbf = (*flagp != 0);
  int idx = blockIdx.x * 256 + threadIdx.x;
  if (idx >= d.base[5]) return;
  int s = 0;
  while (idx >= d.base[s + 1]) s++;
  int local = idx - d.base[s];
  int K = d.K[s], Nc = d.Nc[s];
  int nn = local / K;
  int k = local - nn * K;
  out[idx] = (nn < Nc) ? f2b(rdf(isbf, d.W[s], k * Nc + nn)) : (u16)0;
}

// ---------------- A-fragment load (runtime dtype, exact-zero -> me) ----------------
__device__ __forceinline__ short8 load_a_me(const void* Av, int lda, const void* me,
                                            int r, int k0, int q, bool isbf) {
  short8 a;
  if (isbf) {
    a = *(const short8*)((const u16*)Av + (long)r * lda + k0 + q * 8);
#pragma unroll
    for (int j = 0; j < 8; j++) {
      if (((u16)a[j] & 0x7fffu) == 0)
        a[j] = (short)((const u16*)me)[k0 + q * 8 + j];
    }
  } else {
    const float* A = (const float*)Av;
    const uint4* p = (const uint4*)(A + (long)r * lda + k0 + q * 8);
    uint4 w0 = p[0];
    uint4 w1 = p[1];
    unsigned int ww[8] = {w0.x, w0.y, w0.z, w0.w, w1.x, w1.y, w1.z, w1.w};
#pragma unroll
    for (int j = 0; j < 8; j++) {
      if ((ww[j] & 0x7fffffffu) == 0)
        a[j] = (short)f2b(((const float*)me)[k0 + q * 8 + j]);
      else
        a[j] = (short)f2b(__builtin_bit_cast(float, ww[j]));
    }
  }
  return a;
}

// ------------- fused layer-1 GEMM: tbuf[r] = [ x'@W1e | c'@W1c ]  (64 rows/block) -------------
__global__ __launch_bounds__(256) void gemm_l1(
    const void* __restrict__ x, const void* __restrict__ cc,
    const void* __restrict__ mex, const void* __restrict__ mec,
    const u16* __restrict__ w1e_t, const u16* __restrict__ w1c_t,
    int M, u16* __restrict__ tb, const int* __restrict__ flagp) {
  bool isbf = (*flagp != 0);
  int wid = threadIdx.x >> 6;
  int lane = threadIdx.x & 63;
  int l15 = lane & 15;
  int q = lane >> 4;
  int row0 = blockIdx.x * 64 + wid * 16;
  int r = row0 + l15;
  if (r >= M) r = M - 1;

  floatx4 acce[8], accc[8];
#pragma unroll
  for (int n = 0; n < 8; n++) { acce[n] = (floatx4){0,0,0,0}; accc[n] = (floatx4){0,0,0,0}; }

  for (int k0 = 0; k0 < 256; k0 += 32) {
    short8 a = load_a_me(x, 256, mex, r, k0, q, isbf);
#pragma unroll
    for (int n = 0; n < 8; n++) {
      short8 b = *(const short8*)(w1e_t + (n * 16 + l15) * 256 + k0 + q * 8);
      acce[n] = __builtin_amdgcn_mfma_f32_16x16x32_bf16(a, b, acce[n], 0, 0, 0);
    }
  }
  for (int k0 = 0; k0 < 128; k0 += 32) {
    short8 a = load_a_me(cc, 128, mec, r, k0, q, isbf);
#pragma unroll
    for (int n = 0; n < 8; n++) {
      short8 b = *(const short8*)(w1c_t + (n * 16 + l15) * 128 + k0 + q * 8);
      accc[n] = __builtin_amdgcn_mfma_f32_16x16x32_bf16(a, b, accc[n], 0, 0, 0);
    }
  }
#pragma unroll
  for (int n = 0; n < 8; n++)
#pragma unroll
    for (int rr = 0; rr < 4; rr++) {
      int row = row0 + q * 4 + rr;
      if (row < M) {
        tb[(long)row * 256 + n * 16 + l15] = f2b(acce[n][rr]);
        tb[(long)row * 256 + 128 + n * 16 + l15] = f2b(accc[n][rr]);
      }
    }
}

// ------------- fused layer-2 GEMM: tbuf[r] = [ u_e@W2e | u_c@W2c ]  (A = ubuf bf16) -------------
__global__ __launch_bounds__(256) void gemm_l2(
    const u16* __restrict__ u,
    const u16* __restrict__ w2e_t, const u16* __restrict__ w2c_t,
    int M, u16* __restrict__ tb) {
  int wid = threadIdx.x >> 6;
  int lane = threadIdx.x & 63;
  int l15 = lane & 15;
  int q = lane >> 4;
  int row0 = blockIdx.x * 64 + wid * 16;
  int r = row0 + l15;
  if (r >= M) r = M - 1;

  floatx4 acce[8], accc[8];
#pragma unroll
  for (int n = 0; n < 8; n++) { acce[n] = (floatx4){0,0,0,0}; accc[n] = (floatx4){0,0,0,0}; }

  for (int k0 = 0; k0 < 128; k0 += 32) {
    short8 ae = *(const short8*)(u + (long)r * 256 + k0 + q * 8);
    short8 ac = *(const short8*)(u + (long)r * 256 + 128 + k0 + q * 8);
#pragma unroll
    for (int n = 0; n < 8; n++) {
      short8 be = *(const short8*)(w2e_t + (n * 16 + l15) * 128 + k0 + q * 8);
      short8 bc = *(const short8*)(w2c_t + (n * 16 + l15) * 128 + k0 + q * 8);
      acce[n] = __builtin_amdgcn_mfma_f32_16x16x32_bf16(ae, be, acce[n], 0, 0, 0);
      accc[n] = __builtin_amdgcn_mfma_f32_16x16x32_bf16(ac, bc, accc[n], 0, 0, 0);
    }
  }
#pragma unroll
  for (int n = 0; n < 8; n++)
#pragma unroll
    for (int rr = 0; rr < 4; rr++) {
      int row = row0 + q * 4 + rr;
      if (row < M) {
        tb[(long)row * 256 + n * 16 + l15] = f2b(acce[n][rr]);
        tb[(long)row * 256 + 128 + n * 16 + l15] = f2b(accc[n][rr]);
      }
    }
}

// ------- agg layer-1 (wave per node, 4 feats/lane, uint2, 4-edge unroll; bf16 out) -------
__global__ __launch_bounds__(256) void agg_kernel(
    const u16* __restrict__ t, const int* __restrict__ rowptr, const int* __restrict__ colarr,
    const void* __restrict__ epsE, const void* __restrict__ epsC,
    const void* __restrict__ bE, const void* __restrict__ bC,
    u16* __restrict__ u, int N, const int* __restrict__ flagp) {
  int node = blockIdx.x * 4 + (threadIdx.x >> 6);
  if (node >= N) return;
  bool isbf = (*flagp != 0);
  int lane = threadIdx.x & 63;
  int f0 = lane << 2;
  const u16* tb = t + f0;
  float a0 = 0.f, a1 = 0.f, a2 = 0.f, a3 = 0.f;
  int e = rowptr[node], e1 = rowptr[node + 1];
  for (; e + 4 <= e1; e += 4) {
    int c0 = colarr[e], c1 = colarr[e + 1], c2 = colarr[e + 2], c3 = colarr[e + 3];
    uint2 p0 = *(const uint2*)(tb + ((long)c0 << 8));
    uint2 p1 = *(const uint2*)(tb + ((long)c1 << 8));
    uint2 p2 = *(const uint2*)(tb + ((long)c2 << 8));
    uint2 p3 = *(const uint2*)(tb + ((long)c3 << 8));
    a0 += lo2f(p0.x); a1 += hi2f(p0.x); a2 += lo2f(p0.y); a3 += hi2f(p0.y);
    a0 += lo2f(p1.x); a1 += hi2f(p1.x); a2 += lo2f(p1.y); a3 += hi2f(p1.y);
    a0 += lo2f(p2.x); a1 += hi2f(p2.x); a2 += lo2f(p2.y); a3 += hi2f(p2.y);
    a0 += lo2f(p3.x); a1 += hi2f(p3.x); a2 += lo2f(p3.y); a3 += hi2f(p3.y);
  }
  for (; e < e1; e++) {
    int c = colarr[e];
    uint2 p = *(const uint2*)(tb + ((long)c << 8));
    a0 += lo2f(p.x); a1 += hi2f(p.x); a2 += lo2f(p.y); a3 += hi2f(p.y);
  }
  uint2 ps = *(const uint2*)(tb + ((long)node << 8));
  bool isE = (lane < 32);
  float eps2 = 2.0f + rdf(isbf, isE ? epsE : epsC, 0);
  const void* bp = isE ? bE : bC;
  int bi = isE ? f0 : (f0 - 128);
  a0 = lrelu(a0 + eps2 * lo2f(ps.x) + rdf(isbf, bp, bi + 0));
  a1 = lrelu(a1 + eps2 * hi2f(ps.x) + rdf(isbf, bp, bi + 1));
  a2 = lrelu(a2 + eps2 * lo2f(ps.y) + rdf(isbf, bp, bi + 2));
  a3 = lrelu(a3 + eps2 * hi2f(ps.y) + rdf(isbf, bp, bi + 3));
  uint2 o;
  o.x = ((unsigned int)f2b(a1) << 16) | f2b(a0);
  o.y = ((unsigned int)f2b(a3) << 16) | f2b(a2);
  *(uint2*)(u + ((long)node << 8) + f0) = o;
}

// ------- agg layer-2 + head fused: out[node] = lrelu(u @ Wm + bm), u kept in registers -------
__global__ __launch_bounds__(256) void agg_head(
    const u16* __restrict__ t, const int* __restrict__ rowptr, const int* __restrict__ colarr,
    const void* __restrict__ epsE, const void* __restrict__ epsC,
    const void* __restrict__ bE, const void* __restrict__ bC,
    const u16* __restrict__ wm_t, const void* __restrict__ bm,
    float* __restrict__ out, int N, const int* __restrict__ flagp) {
  __shared__ float wmf[2048];  // [col][f] f32, from wm_t [16][256] (cols 0..7)
  __shared__ float bmf[8];
  bool isbf = (*flagp != 0);
  int tid = threadIdx.x;
  for (int i = tid; i < 2048; i += 256) wmf[i] = b2f((unsigned int)wm_t[i]);
  if (tid < 8) bmf[tid] = rdf(isbf, bm, tid);
  __syncthreads();

  int node = blockIdx.x * 4 + (tid >> 6);
  if (node >= N) return;
  int lane = tid & 63;
  int f0 = lane << 2;
  const u16* tb = t + f0;
  float a0 = 0.f, a1 = 0.f, a2 = 0.f, a3 = 0.f;
  int e = rowptr[node], e1 = rowptr[node + 1];
  for (; e + 4 <= e1; e += 4) {
    int c0 = colarr[e], c1 = colarr[e + 1], c2 = colarr[e + 2], c3 = colarr[e + 3];
    uint2 p0 = *(const uint2*)(tb + ((long)c0 << 8));
    uint2 p1 = *(const uint2*)(tb + ((long)c1 << 8));
    uint2 p2 = *(const uint2*)(tb + ((long)c2 << 8));
    uint2 p3 = *(const uint2*)(tb + ((long)c3 << 8));
    a0 += lo2f(p0.x); a1 += hi2f(p0.x); a2 += lo2f(p0.y); a3 += hi2f(p0.y);
    a0 += lo2f(p1.x); a1 += hi2f(p1.x); a2 += lo2f(p1.y); a3 += hi2f(p1.y);
    a0 += lo2f(p2.x); a1 += hi2f(p2.x); a2 += lo2f(p2.y); a3 += hi2f(p2.y);
    a0 += lo2f(p3.x); a1 += hi2f(p3.x); a2 += lo2f(p3.y); a3 += hi2f(p3.y);
  }
  for (; e < e1; e++) {
    int c = colarr[e];
    uint2 p = *(const uint2*)(tb + ((long)c << 8));
    a0 += lo2f(p.x); a1 += hi2f(p.x); a2 += lo2f(p.y); a3 += hi2f(p.y);
  }
  uint2 ps = *(const uint2*)(tb + ((long)node << 8));
  bool isE = (lane < 32);
  float eps2 = 2.0f + rdf(isbf, isE ? epsE : epsC, 0);
  const void* bp = isE ? bE : bC;
  int bi = isE ? f0 : (f0 - 128);
  a0 = lrelu(a0 + eps2 * lo2f(ps.x) + rdf(isbf, bp, bi + 0));
  a1 = lrelu(a1 + eps2 * hi2f(ps.x) + rdf(isbf, bp, bi + 1));
  a2 = lrelu(a2 + eps2 * lo2f(ps.y) + rdf(isbf, bp, bi + 2));
  a3 = lrelu(a3 + eps2 * hi2f(ps.y) + rdf(isbf, bp, bi + 3));

  // head: p[col] = sum_f u[f] * Wm[f][col]  (per-lane 4-feat partial, then 64-lane butterfly)
  float p[8];
#pragma unroll
  for (int col = 0; col < 8; col++) {
    float4 w = *(const float4*)&wmf[col * 256 + f0];
    p[col] = a0 * w.x + a1 * w.y + a2 * w.z + a3 * w.w;
  }
#pragma unroll
  for (int m = 1; m < 64; m <<= 1) {
#pragma unroll
    for (int col = 0; col < 8; col++) p[col] += __shfl_xor(p[col], m, 64);
  }
  if (lane == 0) {
    float4 o0, o1;
    o0.x = lrelu(p[0] + bmf[0]); o0.y = lrelu(p[1] + bmf[1]);
    o0.z = lrelu(p[2] + bmf[2]); o0.w = lrelu(p[3] + bmf[3]);
    o1.x = lrelu(p[4] + bmf[4]); o1.y = lrelu(p[5] + bmf[5]);
    o1.z = lrelu(p[6] + bmf[6]); o1.w = lrelu(p[7] + bmf[7]);
    *(float4*)(out + (long)node * 8) = o0;
    *(float4*)(out + (long)node * 8 + 4) = o1;
  }
}

// ---------------- central-node MLP (f32 in, f32 out) ----------------
__global__ __launch_bounds__(128) void mlp_kernel(
    const float* __restrict__ outbuf, const int* __restrict__ central,
    const void* __restrict__ Wp1, const void* __restrict__ bp1,
    const void* __restrict__ Wp2, const void* __restrict__ bp2,
    float* __restrict__ logits, const int* __restrict__ flagp) {
  __shared__ float h1[128];
  __shared__ float o[8];
  bool isbf = (*flagp != 0);
  int b = blockIdx.x, tid = threadIdx.x;
  int node = central[b];
  if (tid < 8) o[tid] = outbuf[node * 8 + tid];
  __syncthreads();
  float s = rdf(isbf, bp1, tid);
#pragma unroll
  for (int k = 0; k < 8; k++) s += o[k] * rdf(isbf, Wp1, k * 128 + tid);
  h1[tid] = fmaxf(s, 0.f);
  __syncthreads();
  if (tid < 8) {
    float s2 = rdf(isbf, bp2, tid);
    for (int k = 0; k < 128; k++) s2 += h1[k] * rdf(isbf, Wp2, k * 8 + tid);
    logits[b * 8 + tid] = s2;
  }
}

extern "C" void kernel_launch(void* const* d_in, const int* in_sizes, int n_in,
                              void* d_out, int out_size, void* d_ws, size_t ws_size,
                              hipStream_t stream) {
  const void* x    = d_in[0];
  const void* c    = d_in[1];
  const int* eidx  = (const int*)d_in[2];
  const int* cidx  = (const int*)d_in[3];
  const void* me_x = d_in[4];
  const void* me_c = d_in[5];
  const void* W1e  = d_in[6];
  const void* b1e  = d_in[7];
  const void* e1e  = d_in[8];
  const void* W2e  = d_in[9];
  const void* b2e  = d_in[10];
  const void* e2e  = d_in[11];
  const void* W1c  = d_in[12];
  const void* b1c  = d_in[13];
  const void* e1c  = d_in[14];
  const void* W2c  = d_in[15];
  const void* b2c  = d_in[16];
  const void* e2c  = d_in[17];
  const void* Wm   = d_in[18];
  const void* bm   = d_in[19];
  const void* Wp1  = d_in[20];
  const void* bp1  = d_in[21];
  const void* Wp2  = d_in[22];
  const void* bp2  = d_in[23];

  const int N = in_sizes[0] / 256;   // 50000
  const int E = in_sizes[2] / 2;     // 800000
  const int Cn = in_sizes[3];        // 512
  const int* src = eidx;
  const int* dst = eidx + E;

  char* ws = (char*)d_ws;
  int* deg    = (int*)(ws + 0);          // 200000 B
  int* rowptr = (int*)(ws + 200192);     // 200004 B
  int* cursor = (int*)(ws + 400384);     // 200000 B
  int* colarr = (int*)(ws + 600576);     // 3200000 B
  u16* tbuf   = (u16*)(ws + 3800576);    // 25600000 B  [N,256] bf16
  u16* ubuf   = (u16*)(ws + 29400576);   // 25600000 B  [N,256] bf16
  u16* wt_all = (u16*)(ws + 55000576);   // 172032 B
  int* flag   = (int*)(ws + 55172608);   // 4 B
  int* bsum   = (int*)(ws + 55172864);   // 256 B
  int* boff   = (int*)(ws + 55173120);   // 256 B

  u16* w1e_t = wt_all + 0;       // [128][256]
  u16* w1c_t = wt_all + 32768;   // [128][128]
  u16* w2e_t = wt_all + 49152;   // [128][128]
  u16* w2c_t = wt_all + 65536;   // [128][128]
  u16* wm_t  = wt_all + 81920;   // [16][256]

  // init: zero deg + dtype detect
  init_kernel<<<(N + 1023) / 1024, 256, 0, stream>>>(deg, N, (const u16*)x, flag);

  // CSR build
  hist_kernel<<<(E + 255) / 256, 256, 0, stream>>>(dst, E, deg);
  int PB = (N + SCB - 1) / SCB;  // 49
  scan_phaseA<<<PB, 256, 0, stream>>>(deg, bsum, N);
  scan_phaseB<<<1, 64, 0, stream>>>(bsum, boff, PB, rowptr, N);
  scan_phaseC<<<PB, 256, 0, stream>>>(deg, boff, rowptr, cursor, N);
  fill_kernel<<<(E + 255) / 256, 256, 0, stream>>>(src, dst, E, cursor, colarr);

  // weight transposes
  TWDesc td;
  td.W[0] = W1e; td.K[0] = 256; td.Nc[0] = 128;
  td.W[1] = W1c; td.K[1] = 128; td.Nc[1] = 128;
  td.W[2] = W2e; td.K[2] = 128; td.Nc[2] = 128;
  td.W[3] = W2c; td.K[3] = 128; td.Nc[3] = 128;
  td.W[4] = Wm;  td.K[4] = 256; td.Nc[4] = 8;
  td.base[0] = 0; td.base[1] = 32768; td.base[2] = 49152;
  td.base[3] = 65536; td.base[4] = 81920; td.base[5] = 86016;
  transpose_all<<<(86016 + 255) / 256, 256, 0, stream>>>(td, wt_all, flag);

  int gb = (N + 63) / 64;  // 782
  // layer 1 (fused e+c)
  gemm_l1<<<gb, 256, 0, stream>>>(x, c, me_x, me_c, w1e_t, w1c_t, N, tbuf, flag);
  agg_kernel<<<(N + 3) / 4, 256, 0, stream>>>(tbuf, rowptr, colarr,
      e1e, e1c, b1e, b1c, ubuf, N, flag);
  // layer 2 (fused e+c)
  gemm_l2<<<gb, 256, 0, stream>>>(ubuf, w2e_t, w2c_t, N, tbuf);
  // agg2 + head fused -> d_out[0 : N*8] f32
  agg_head<<<(N + 3) / 4, 256, 0, stream>>>(tbuf, rowptr, colarr,
      e2e, e2c, b2e, b2c, wm_t, bm, (float*)d_out, N, flag);
  // central MLP -> d_out[N*8 : ...]
  mlp_kernel<<<Cn, 128, 0, stream>>>((const float*)d_out, cidx,
      Wp1, bp1, Wp2, bp2, (float*)d_out + (size_t)N * 8, flag);
}